// Round 11
// baseline (113.868 us; speedup 1.0000x reference)
//
#include <hip/hip_runtime.h>
#include <hip/hip_bf16.h>
#include <math.h>
#include <stdint.h>

#define NB 4
#define NQ 100
#define NQR 101                   // partial rows: 100 queries + ones-row (Stm)
#define NCLS 81
#define NT 20
#define NHW 65536

#define SC 256                    // split-K chunks: one 256-px output row each
#define CPX (NHW / SC)            // 256 px per block

typedef __attribute__((ext_vector_type(8))) short bf16x8;
typedef __attribute__((ext_vector_type(16))) float f32x16;

__device__ inline short to_bf16(float f) {
    __hip_bfloat16 h = __float2bfloat16(f);   // RNE; pairs fuse to v_cvt_pk_bf16_f32
    return __builtin_bit_cast(short, h);
}

// v_exp_f32 / v_log_f32 are base-2 on gfx950
__device__ inline float fast_exp2(float x) { return __builtin_amdgcn_exp2f(x); }
__device__ inline float fast_log2(float x) { return __builtin_amdgcn_logf(x); }

// ---------------------------------------------------------------------------
// Kernel 1: fused main pass (structure unchanged from R10; only the partial
// layout is now chunk-major: A_part[((b*NQR+q)*21+t)*SC + chunk]).
// ---------------------------------------------------------------------------
__global__ void __launch_bounds__(256)
k_main(const float* __restrict__ pm, const float* __restrict__ tgt,
       float* __restrict__ A_part, float* __restrict__ D_part,
       float* __restrict__ Sp_part) {
    int gid = blockIdx.x;
    int chunk = gid & (SC - 1);           // == output row h
    int b = gid >> 8;
    int tid = threadIdx.x;
    int wv = tid >> 6, lane = tid & 63;
    int p0 = chunk * CPX;

    __shared__ uint32_t s_tb[CPX];        // 1 KB tbits
    __shared__ float s_pm[128 * 64];      // 32 KB staged pm sub-tile (swizzled)
    __shared__ short s_bf[4][512];        // 4 KB B-frags (current sub-tile)

    // ---- phase A: gather + tbits ----
    if (tid < 128) {
        const float* base = tgt + (((size_t)b * NT) * 512 + 2 * chunk) * 512 + 4 * tid;
        uint32_t w0 = 0, w1 = 0;
#pragma unroll
        for (int t = 0; t < NT; ++t) {
            float4 v = *reinterpret_cast<const float4*>(base + (size_t)t * 512 * 512);
            w0 |= (v.x > 0.5f ? 1u : 0u) << t;
            w1 |= (v.z > 0.5f ? 1u : 0u) << t;
        }
        s_tb[2 * tid] = w0;
        s_tb[2 * tid + 1] = w1;
    }
    __syncthreads();

    int r0 = tid >> 4, cw = tid & 15;     // staging: row base, 16B-chunk index
    int Rg = wv * 32 + (lane & 31);       // this lane's query row (0..127)
    int h = lane >> 5;
    const bool ones_row = (Rg == NQ);     // row 100: A-frag = all ones -> Stm
    bf16x8 ones;
#pragma unroll
    for (int e = 0; e < 8; ++e) ones[e] = (short)0x3F80;

    f32x16 accA, accD;
#pragma unroll
    for (int r = 0; r < 16; ++r) { accA[r] = 0.0f; accD[r] = 0.0f; }
    float mxsum = 0.0f, l2sum = 0.0f;
    const float LOG2E = 1.4426950408889634f;

    for (int st = 0; st < 4; ++st) {
        // ---- B-frags for k-steps st*4..st*4+3 ----
        {
            int ls = wv;
            int col = lane & 31;
            int kbase = st * 64 + ls * 16 + (h << 3);
            uint32_t pk[4];
#pragma unroll
            for (int e2 = 0; e2 < 4; ++e2) {
                uint32_t w0 = s_tb[kbase + 2 * e2];
                uint32_t w1 = s_tb[kbase + 2 * e2 + 1];
                uint32_t lo, hi;
                if (col < NT)       { lo = ((w0 >> col) & 1u) ? 0x3F80u : 0u;
                                      hi = ((w1 >> col) & 1u) ? 0x3F80u : 0u; }
                else if (col == NT) { lo = 0x3F80u; hi = 0x3F80u; }   // ones col
                else                { lo = 0u; hi = 0u; }
                pk[e2] = lo | (hi << 16);
            }
            *reinterpret_cast<uint4*>(&s_bf[ls][lane * 8]) =
                *reinterpret_cast<const uint4*>(pk);
        }
        // ---- stage pm sub-tile (coalesced) ----
#pragma unroll
        for (int p = 0; p < 8; ++p) {
            int row = r0 + 16 * p;
            int srow = (row < NQ) ? row : 0;
            float4 v = *reinterpret_cast<const float4*>(
                pm + ((size_t)(b * NQ + srow)) * NHW + (p0 + st * 64 + cw * 4));
            *reinterpret_cast<float4*>(
                &s_pm[row * 64 + ((cw ^ (row & 7)) << 2)]) = v;
        }
        __syncthreads();
        // ---- compute 4 k-steps ----
#pragma unroll
        for (int sl = 0; sl < 4; ++sl) {
            int c0 = sl * 4 + h * 2;
            float4 xa = *reinterpret_cast<const float4*>(
                &s_pm[Rg * 64 + ((c0 ^ (Rg & 7)) << 2)]);
            float4 xb4 = *reinterpret_cast<const float4*>(
                &s_pm[Rg * 64 + (((c0 + 1) ^ (Rg & 7)) << 2)]);
            float xs[8] = {xa.x, xa.y, xa.z, xa.w, xb4.x, xb4.y, xb4.z, xb4.w};
            bf16x8 af, sf;
#pragma unroll
            for (int e = 0; e < 8; ++e) {
                float xi = xs[e];
                float y = xi * LOG2E;
                float e1 = fast_exp2(0.0f - fabsf(y));  // exp(-|x|)
                float tt = 1.0f + e1;
                float inv = __builtin_amdgcn_rcpf(tt);
                float sig = (xi >= 0.0f) ? inv : e1 * inv;
                l2sum += fast_log2(tt);                 // softplus=max(x,0)+ln2*log2
                mxsum += fmaxf(xi, 0.0f);
                af[e] = to_bf16(xi);
                sf[e] = to_bf16(sig);
            }
            if (ones_row) af = ones;
            bf16x8 bf = *reinterpret_cast<const bf16x8*>(&s_bf[sl][lane * 8]);
            accA = __builtin_amdgcn_mfma_f32_32x32x16_bf16(af, bf, accA, 0, 0, 0);
            accD = __builtin_amdgcn_mfma_f32_32x32x16_bf16(sf, bf, accD, 0, 0, 0);
        }
        __syncthreads();
    }

    // Epilogue: C/D layout: col = lane&31, row = (r&3)+8*(r>>2)+4*(lane>>5)
    // Chunk-major partials: [(b*NQR+q)*21+t][chunk]
    int t = lane & 31;
#pragma unroll
    for (int r = 0; r < 16; ++r) {
        int rowD = (r & 3) + 8 * (r >> 2) + 4 * (lane >> 5);
        int qo = wv * 32 + rowD;
        if (qo <= NQ && t <= NT) {      // qo==100 is the ones/Stm row
            size_t base = ((size_t)(b * NQR + qo) * (NT + 1) + t) * SC + chunk;
            A_part[base] = accA[r];
            D_part[base] = accD[r];
        }
    }
    float sp = fmaf(0.6931471805599453f, l2sum, mxsum);
    sp += __shfl_xor(sp, 32);
    if (lane < 32 && Rg < NQ)
        Sp_part[(size_t)(b * NQ + Rg) * SC + chunk] = sp;
}

// ---------------------------------------------------------------------------
// Kernel 2: assemble C[b,q,t]. One block (256 threads) per (b,q).
// 64 reduction rows of 256 contiguous floats: 0..20 = A[t], 21..41 = D[t],
// 42..62 = Stm[t] (A ones-row), 63 = Sp. Each wave reduces 16 rows coalesced.
// ---------------------------------------------------------------------------
__global__ void __launch_bounds__(256)
k_assemble(const float* __restrict__ logits, const int* __restrict__ labels,
           const float* __restrict__ A_part, const float* __restrict__ D_part,
           const float* __restrict__ Sp_part, float* __restrict__ Cout) {
    int bq = blockIdx.x;
    int q = bq % NQ, b = bq / NQ;
    int tid = threadIdx.x, wv = tid >> 6, lane = tid & 63;
    __shared__ float red[64];

    for (int rr = 0; rr < 16; ++rr) {
        int row = wv * 16 + rr;
        const float* p;
        if (row < 21)      p = A_part + ((size_t)(b * NQR + q) * (NT + 1) + row) * SC;
        else if (row < 42) p = D_part + ((size_t)(b * NQR + q) * (NT + 1) + (row - 21)) * SC;
        else if (row < 63) p = A_part + ((size_t)(b * NQR + NQ) * (NT + 1) + (row - 42)) * SC;
        else               p = Sp_part + (size_t)(b * NQ + q) * SC;
        float s = p[lane] + p[lane + 64] + p[lane + 128] + p[lane + 192];
        for (int o = 32; o; o >>= 1) s += __shfl_xor(s, o);
        if (lane == 0) red[row] = s;
    }
    __syncthreads();

    if (wv == 0) {
        int lt = (lane < 21) ? lane : 0;
        float At4 = red[lt];
        float Dt4 = red[21 + lt];
        float St4 = red[42 + lt];
        float Sneg = red[63];
        float Ssig = red[41];                       // D at t=20 (ones column)

        const float* lg = logits + (size_t)bq * NCLS;
        float x0 = (lane < NCLS) ? lg[lane] : -INFINITY;
        float x1 = (lane + 64 < NCLS) ? lg[lane + 64] : -INFINITY;
        float mx = fmaxf(x0, x1);
        for (int o = 32; o; o >>= 1) mx = fmaxf(mx, __shfl_xor(mx, o));
        float s0 = (lane < NCLS) ? __expf(x0 - mx) : 0.0f;
        float s1 = (lane + 64 < NCLS) ? __expf(x1 - mx) : 0.0f;
        float sum = s0 + s1;
        for (int o = 32; o; o >>= 1) sum += __shfl_xor(sum, o);

        if (lane < NT) {
            int label = labels[b * NT + lane];
            float prob = __expf(lg[label] - mx) / sum;
            float cm = (Sneg - At4) * (1.0f / (float)NHW);
            float cd = 1.0f - (2.0f * Dt4 + 1.0f) / (Ssig + St4 + 1.0f);
            float c = 2.0f * (-prob) + 5.0f * cm + 5.0f * cd;
            if (isnan(c)) c = 0.0f;
            Cout[(size_t)bq * NT + lane] = c;
        }
    }
}

// ---------------------------------------------------------------------------
// Kernel 3: LSA (scipy shortest augmenting path, float64) on C[b].T
// (rows = 20 targets, cols = 100 queries). ONE WAVE per batch, ZERO barriers
// in the hot loop: lane L owns columns L and L+64 (v/shortest/path/covered/
// row4col in registers); lanes<20 own u/col4row; scalars via __shfl
// broadcast; per-lane-index gathers via __shfl (ds_bpermute). Cost matrix in
// LDS, read per-lane. Exact scipy op order; numpy argmin tie-break (lowest j).
// ---------------------------------------------------------------------------
__global__ void __launch_bounds__(64)
k_lsa(const float* __restrict__ Cmat, float* __restrict__ out) {
    int b = blockIdx.x;
    int lane = threadIdx.x;
    __shared__ double s_cost[NT][128];

    for (int idx = lane; idx < NT * 128; idx += 64) {
        int r = idx >> 7, j = idx & 127;
        s_cost[r][j] = (j < NQ) ? (double)Cmat[((size_t)b * NQ + j) * NT + r] : 0.0;
    }
    __syncthreads();   // once; hot loop below is barrier-free (single wave)

    int j0 = lane, j1 = lane + 64;
    bool v1ok = (j1 < NQ);                  // lanes 0..35 own a second column
    double v_0 = 0.0, v_1 = 0.0;
    int r4c0 = -1, r4c1 = -1;               // row4col for owned columns
    double u_r = 0.0;                       // lanes<NT: u[lane]
    int c4r = -1;                           // lanes<NT: col4row[lane]

    for (int cur = 0; cur < NT; ++cur) {
        double sh0 = INFINITY, sh1 = INFINITY;
        int p0 = -1, p1 = -1;
        bool sc0 = false, sc1 = false;      // covered
        bool SRr = false;                   // lanes<NT: row in SR
        int i = cur, sink = -1;
        double minVal = 0.0;

        while (true) {
            if (lane == i) SRr = true;
            double ui = __shfl(u_r, i);
            double c0 = s_cost[i][j0];
            double c1 = s_cost[i][j1 & 127];
            if (!sc0) {
                double d = (minVal + c0 - ui) - v_0;
                if (d < sh0) { sh0 = d; p0 = i; }
            }
            if (v1ok && !sc1) {
                double d = (minVal + c1 - ui) - v_1;
                if (d < sh1) { sh1 = d; p1 = i; }
            }
            // per-lane candidate among its uncovered columns (tie -> lower j)
            double cand0 = (!sc0) ? sh0 : INFINITY;
            double cand1 = (v1ok && !sc1) ? sh1 : INFINITY;
            double bv; int bj;
            if (cand0 <= cand1) { bv = cand0; bj = j0; }
            else                { bv = cand1; bj = j1; }
            for (int o = 32; o; o >>= 1) {
                double ov = __shfl_xor(bv, o);
                int oj = __shfl_xor(bj, o);
                if (ov < bv || (ov == bv && oj < bj)) { bv = ov; bj = oj; }
            }
            minVal = bv;
            if (bj < 64) { if (lane == bj) sc0 = true; }
            else         { if (lane == bj - 64) sc1 = true; }
            int r4 = (bj < 64) ? __shfl(r4c0, bj) : __shfl(r4c1, bj - 64);
            if (r4 == -1) { sink = bj; break; }
            i = r4;
        }

        // dual updates (reference op order)
        {
            int c = c4r;                                    // per-lane index
            double g0 = __shfl(sh0, c & 63);
            double g1 = __shfl(sh1, (c - 64) & 63);
            double shc = (c < 64) ? g0 : g1;
            if (lane == cur) u_r += minVal;
            else if (lane < NT && SRr) u_r += minVal - shc;
        }
        if (sc0) v_0 -= minVal - sh0;
        if (v1ok && sc1) v_1 -= minVal - sh1;

        // augmenting chain (wave-uniform serial)
        int j = sink;
        while (true) {
            int ii = (j < 64) ? __shfl(p0, j) : __shfl(p1, j - 64);
            if (j < 64) { if (lane == j) r4c0 = ii; }
            else        { if (lane == j - 64) r4c1 = ii; }
            int nj = __shfl(c4r, ii);
            if (lane == ii) c4r = j;
            if (ii == cur) break;
            j = nj;
        }
    }

    // outputs: sort (q,t) pairs by assigned query via rank-counting
    int my = c4r;
    int rank = 0;
#pragma unroll
    for (int t2 = 0; t2 < NT; ++t2) {
        int vv = __shfl(my, t2);
        rank += (vv < my) ? 1 : 0;
    }
    if (lane < NT) {
        out[NB * NQ * NT + b * NT + rank] = (float)my;              // pred_idx
        out[NB * NQ * NT + NB * NT + b * NT + rank] = (float)lane;  // tgt_idx
    }
}

// ---------------------------------------------------------------------------
extern "C" void kernel_launch(void* const* d_in, const int* in_sizes, int n_in,
                              void* d_out, int out_size, void* d_ws, size_t ws_size,
                              hipStream_t stream) {
    const float* pred_logits = (const float*)d_in[0];   // [4,100,81]
    const float* pred_masks  = (const float*)d_in[1];   // [4,100,256,256]
    const float* tgt_masks   = (const float*)d_in[2];   // [4,20,512,512]
    const int*   tgt_labels  = (const int*)d_in[3];     // [4,20]
    float* out = (float*)d_out;

    char* ws = (char*)d_ws;
    float* A_part  = (float*)ws;                                      // NB*NQR*21*SC
    float* D_part  = A_part + (size_t)NB * NQR * (NT + 1) * SC;
    float* Sp_part = D_part + (size_t)NB * NQR * (NT + 1) * SC;       // NB*NQ*SC

    k_main<<<NB * SC, 256, 0, stream>>>(pred_masks, tgt_masks, A_part, D_part, Sp_part);
    k_assemble<<<NB * NQ, 256, 0, stream>>>(pred_logits, tgt_labels, A_part, D_part,
                                            Sp_part, out);
    k_lsa<<<NB, 64, 0, stream>>>(out, out);
}

// Round 12
// 79.650 us; speedup vs baseline: 1.4296x; 1.4296x over previous
//
#include <hip/hip_runtime.h>
#include <hip/hip_bf16.h>
#include <math.h>
#include <stdint.h>

#define NB 4
#define NQ 100
#define NQR 101                   // partial rows: 100 queries + ones-row (Stm)
#define NCLS 81
#define NT 20
#define NHW 65536

#define SC 256                    // split-K chunks: one 256-px output row each
#define CPX (NHW / SC)            // 256 px per block
#define TP 32                     // padded t-dim (21 -> 32) for coalescing

typedef __attribute__((ext_vector_type(8))) short bf16x8;
typedef __attribute__((ext_vector_type(16))) float f32x16;

__device__ inline short to_bf16(float f) {
    __hip_bfloat16 h = __float2bfloat16(f);   // RNE; pairs fuse to v_cvt_pk_bf16_f32
    return __builtin_bit_cast(short, h);
}

// v_exp_f32 / v_log_f32 are base-2 on gfx950
__device__ inline float fast_exp2(float x) { return __builtin_amdgcn_exp2f(x); }
__device__ inline float fast_log2(float x) { return __builtin_amdgcn_logf(x); }

// ---------------------------------------------------------------------------
// Kernel 1: fused main pass (phases unchanged from R10 — the 62 µs variant).
// Partials layout: A_part[((b*NQR+q)*SC + chunk)*TP + t]  — epilogue writes
// are 84 B contiguous runs (no write-allocate scatter); k_assemble slabs are
// 32 KB contiguous per (b,q).
// ---------------------------------------------------------------------------
__global__ void __launch_bounds__(256)
k_main(const float* __restrict__ pm, const float* __restrict__ tgt,
       float* __restrict__ A_part, float* __restrict__ D_part,
       float* __restrict__ Sp_part) {
    int gid = blockIdx.x;
    int chunk = gid & (SC - 1);           // == output row h
    int b = gid >> 8;
    int tid = threadIdx.x;
    int wv = tid >> 6, lane = tid & 63;
    int p0 = chunk * CPX;

    __shared__ uint32_t s_tb[CPX];        // 1 KB tbits
    __shared__ float s_pm[128 * 64];      // 32 KB staged pm sub-tile (swizzled)
    __shared__ short s_bf[4][512];        // 4 KB B-frags (current sub-tile)

    // ---- phase A: gather + tbits ----
    if (tid < 128) {
        const float* base = tgt + (((size_t)b * NT) * 512 + 2 * chunk) * 512 + 4 * tid;
        uint32_t w0 = 0, w1 = 0;
#pragma unroll
        for (int t = 0; t < NT; ++t) {
            float4 v = *reinterpret_cast<const float4*>(base + (size_t)t * 512 * 512);
            w0 |= (v.x > 0.5f ? 1u : 0u) << t;
            w1 |= (v.z > 0.5f ? 1u : 0u) << t;
        }
        s_tb[2 * tid] = w0;
        s_tb[2 * tid + 1] = w1;
    }
    __syncthreads();

    int r0 = tid >> 4, cw = tid & 15;     // staging: row base, 16B-chunk index
    int Rg = wv * 32 + (lane & 31);       // this lane's query row (0..127)
    int h = lane >> 5;
    const bool ones_row = (Rg == NQ);     // row 100: A-frag = all ones -> Stm
    bf16x8 ones;
#pragma unroll
    for (int e = 0; e < 8; ++e) ones[e] = (short)0x3F80;

    f32x16 accA, accD;
#pragma unroll
    for (int r = 0; r < 16; ++r) { accA[r] = 0.0f; accD[r] = 0.0f; }
    float mxsum = 0.0f, l2sum = 0.0f;
    const float LOG2E = 1.4426950408889634f;

    for (int st = 0; st < 4; ++st) {
        // ---- B-frags for k-steps st*4..st*4+3 ----
        {
            int ls = wv;
            int col = lane & 31;
            int kbase = st * 64 + ls * 16 + (h << 3);
            uint32_t pk[4];
#pragma unroll
            for (int e2 = 0; e2 < 4; ++e2) {
                uint32_t w0 = s_tb[kbase + 2 * e2];
                uint32_t w1 = s_tb[kbase + 2 * e2 + 1];
                uint32_t lo, hi;
                if (col < NT)       { lo = ((w0 >> col) & 1u) ? 0x3F80u : 0u;
                                      hi = ((w1 >> col) & 1u) ? 0x3F80u : 0u; }
                else if (col == NT) { lo = 0x3F80u; hi = 0x3F80u; }   // ones col
                else                { lo = 0u; hi = 0u; }
                pk[e2] = lo | (hi << 16);
            }
            *reinterpret_cast<uint4*>(&s_bf[ls][lane * 8]) =
                *reinterpret_cast<const uint4*>(pk);
        }
        // ---- stage pm sub-tile (coalesced) ----
#pragma unroll
        for (int p = 0; p < 8; ++p) {
            int row = r0 + 16 * p;
            int srow = (row < NQ) ? row : 0;
            float4 v = *reinterpret_cast<const float4*>(
                pm + ((size_t)(b * NQ + srow)) * NHW + (p0 + st * 64 + cw * 4));
            *reinterpret_cast<float4*>(
                &s_pm[row * 64 + ((cw ^ (row & 7)) << 2)]) = v;
        }
        __syncthreads();
        // ---- compute 4 k-steps ----
#pragma unroll
        for (int sl = 0; sl < 4; ++sl) {
            int c0 = sl * 4 + h * 2;
            float4 xa = *reinterpret_cast<const float4*>(
                &s_pm[Rg * 64 + ((c0 ^ (Rg & 7)) << 2)]);
            float4 xb4 = *reinterpret_cast<const float4*>(
                &s_pm[Rg * 64 + (((c0 + 1) ^ (Rg & 7)) << 2)]);
            float xs[8] = {xa.x, xa.y, xa.z, xa.w, xb4.x, xb4.y, xb4.z, xb4.w};
            bf16x8 af, sf;
#pragma unroll
            for (int e = 0; e < 8; ++e) {
                float xi = xs[e];
                float y = xi * LOG2E;
                float e1 = fast_exp2(0.0f - fabsf(y));  // exp(-|x|)
                float tt = 1.0f + e1;
                float inv = __builtin_amdgcn_rcpf(tt);
                float sig = (xi >= 0.0f) ? inv : e1 * inv;
                l2sum += fast_log2(tt);                 // softplus=max(x,0)+ln2*log2
                mxsum += fmaxf(xi, 0.0f);
                af[e] = to_bf16(xi);
                sf[e] = to_bf16(sig);
            }
            if (ones_row) af = ones;
            bf16x8 bf = *reinterpret_cast<const bf16x8*>(&s_bf[sl][lane * 8]);
            accA = __builtin_amdgcn_mfma_f32_32x32x16_bf16(af, bf, accA, 0, 0, 0);
            accD = __builtin_amdgcn_mfma_f32_32x32x16_bf16(sf, bf, accD, 0, 0, 0);
        }
        __syncthreads();
    }

    // Epilogue: C/D layout: col = lane&31, row = (r&3)+8*(r>>2)+4*(lane>>5)
    int t = lane & 31;
#pragma unroll
    for (int r = 0; r < 16; ++r) {
        int rowD = (r & 3) + 8 * (r >> 2) + 4 * (lane >> 5);
        int qo = wv * 32 + rowD;
        if (qo <= NQ && t <= NT) {      // qo==100 is the ones/Stm row
            size_t base = ((size_t)(b * NQR + qo) * SC + chunk) * TP + t;
            A_part[base] = accA[r];
            D_part[base] = accD[r];
        }
    }
    float sp = fmaf(0.6931471805599453f, l2sum, mxsum);
    sp += __shfl_xor(sp, 32);
    if (lane < 32 && Rg < NQ)
        Sp_part[(size_t)(b * NQ + Rg) * SC + chunk] = sp;
}

// ---------------------------------------------------------------------------
// Kernel 2: assemble C[b,q,t]. One block (256 threads) per (b,q).
// Per-(b,q) slabs are contiguous: A/D [SC][TP], Sp [SC]. Thread (g=tid>>5,
// t=tid&31) reduces chunks g, g+8, ... fully coalesced (128 B per 32-thread
// group); combine across g via shfl(32) + LDS; wave 0 does the epilogue.
// ---------------------------------------------------------------------------
__global__ void __launch_bounds__(256)
k_assemble(const float* __restrict__ logits, const int* __restrict__ labels,
           const float* __restrict__ A_part, const float* __restrict__ D_part,
           const float* __restrict__ Sp_part, float* __restrict__ Cout) {
    int bq = blockIdx.x;
    int q = bq % NQ, b = bq / NQ;
    int tid = threadIdx.x, wv = tid >> 6, lane = tid & 63;
    int t = tid & 31, g = tid >> 5;       // chunk-group 0..7
    __shared__ float sA[4][32], sD[4][32], sS[4][32], sSn[4];

    const float* pa = A_part + (size_t)(b * NQR + q) * SC * TP;
    const float* pd = D_part + (size_t)(b * NQR + q) * SC * TP;
    const float* ps = A_part + (size_t)(b * NQR + NQ) * SC * TP;   // ones-row -> Stm
    const float* pp = Sp_part + (size_t)(b * NQ + q) * SC;

    float a = 0.0f, d = 0.0f, s = 0.0f;
    for (int c = g; c < SC; c += 8) {
        a += pa[c * TP + t];
        d += pd[c * TP + t];
        s += ps[c * TP + t];
    }
    // combine the two chunk-groups within each wave (lane>>5)
    a += __shfl_xor(a, 32);
    d += __shfl_xor(d, 32);
    s += __shfl_xor(s, 32);
    if (lane < 32) { sA[wv][lane] = a; sD[wv][lane] = d; sS[wv][lane] = s; }
    {   // Sneg: 256 contiguous floats
        float sp = pp[tid & 255 & (SC - 1)];   // tid 0..255 -> chunk tid
        for (int o = 32; o; o >>= 1) sp += __shfl_xor(sp, o);
        if (lane == 0) sSn[wv] = sp;
    }
    __syncthreads();

    if (wv == 0) {
        int lt = (lane < 32) ? lane : 0;
        float At4 = sA[0][lt] + sA[1][lt] + sA[2][lt] + sA[3][lt];
        float Dt4 = sD[0][lt] + sD[1][lt] + sD[2][lt] + sD[3][lt];
        float St4 = sS[0][lt] + sS[1][lt] + sS[2][lt] + sS[3][lt];
        float Sneg = sSn[0] + sSn[1] + sSn[2] + sSn[3];
        float Ssig = __shfl(Dt4, NT);                 // ones-column of D-GEMM

        const float* lg = logits + (size_t)bq * NCLS;
        float x0 = (lane < NCLS) ? lg[lane] : -INFINITY;
        float x1 = (lane + 64 < NCLS) ? lg[lane + 64] : -INFINITY;
        float mx = fmaxf(x0, x1);
        for (int o = 32; o; o >>= 1) mx = fmaxf(mx, __shfl_xor(mx, o));
        float s0 = (lane < NCLS) ? __expf(x0 - mx) : 0.0f;
        float s1 = (lane + 64 < NCLS) ? __expf(x1 - mx) : 0.0f;
        float sum = s0 + s1;
        for (int o = 32; o; o >>= 1) sum += __shfl_xor(sum, o);

        if (lane < NT) {
            int label = labels[b * NT + lane];
            float prob = __expf(lg[label] - mx) / sum;
            float cm = (Sneg - At4) * (1.0f / (float)NHW);
            float cd = 1.0f - (2.0f * Dt4 + 1.0f) / (Ssig + St4 + 1.0f);
            float c = 2.0f * (-prob) + 5.0f * cm + 5.0f * cd;
            if (isnan(c)) c = 0.0f;
            Cout[(size_t)bq * NT + lane] = c;
        }
    }
}

// ---------------------------------------------------------------------------
// Kernel 3: LSA (scipy shortest augmenting path, float64) on C[b].T
// (rows = 20 targets, cols = 100 queries). ONE WAVE per batch, ZERO barriers
// in the hot loop (verified R11). Exact scipy op order; numpy tie-break.
// ---------------------------------------------------------------------------
__global__ void __launch_bounds__(64)
k_lsa(const float* __restrict__ Cmat, float* __restrict__ out) {
    int b = blockIdx.x;
    int lane = threadIdx.x;
    __shared__ double s_cost[NT][128];

    for (int idx = lane; idx < NT * 128; idx += 64) {
        int r = idx >> 7, j = idx & 127;
        s_cost[r][j] = (j < NQ) ? (double)Cmat[((size_t)b * NQ + j) * NT + r] : 0.0;
    }
    __syncthreads();   // once; hot loop below is barrier-free (single wave)

    int j0 = lane, j1 = lane + 64;
    bool v1ok = (j1 < NQ);
    double v_0 = 0.0, v_1 = 0.0;
    int r4c0 = -1, r4c1 = -1;
    double u_r = 0.0;
    int c4r = -1;

    for (int cur = 0; cur < NT; ++cur) {
        double sh0 = INFINITY, sh1 = INFINITY;
        int p0 = -1, p1 = -1;
        bool sc0 = false, sc1 = false;
        bool SRr = false;
        int i = cur, sink = -1;
        double minVal = 0.0;

        while (true) {
            if (lane == i) SRr = true;
            double ui = __shfl(u_r, i);
            double c0 = s_cost[i][j0];
            double c1 = s_cost[i][j1 & 127];
            if (!sc0) {
                double d = (minVal + c0 - ui) - v_0;
                if (d < sh0) { sh0 = d; p0 = i; }
            }
            if (v1ok && !sc1) {
                double d = (minVal + c1 - ui) - v_1;
                if (d < sh1) { sh1 = d; p1 = i; }
            }
            double cand0 = (!sc0) ? sh0 : INFINITY;
            double cand1 = (v1ok && !sc1) ? sh1 : INFINITY;
            double bv; int bj;
            if (cand0 <= cand1) { bv = cand0; bj = j0; }
            else                { bv = cand1; bj = j1; }
            for (int o = 32; o; o >>= 1) {
                double ov = __shfl_xor(bv, o);
                int oj = __shfl_xor(bj, o);
                if (ov < bv || (ov == bv && oj < bj)) { bv = ov; bj = oj; }
            }
            minVal = bv;
            if (bj < 64) { if (lane == bj) sc0 = true; }
            else         { if (lane == bj - 64) sc1 = true; }
            int r4 = (bj < 64) ? __shfl(r4c0, bj) : __shfl(r4c1, bj - 64);
            if (r4 == -1) { sink = bj; break; }
            i = r4;
        }

        {
            int c = c4r;
            double g0 = __shfl(sh0, c & 63);
            double g1 = __shfl(sh1, (c - 64) & 63);
            double shc = (c < 64) ? g0 : g1;
            if (lane == cur) u_r += minVal;
            else if (lane < NT && SRr) u_r += minVal - shc;
        }
        if (sc0) v_0 -= minVal - sh0;
        if (v1ok && sc1) v_1 -= minVal - sh1;

        int j = sink;
        while (true) {
            int ii = (j < 64) ? __shfl(p0, j) : __shfl(p1, j - 64);
            if (j < 64) { if (lane == j) r4c0 = ii; }
            else        { if (lane == j - 64) r4c1 = ii; }
            int nj = __shfl(c4r, ii);
            if (lane == ii) c4r = j;
            if (ii == cur) break;
            j = nj;
        }
    }

    int my = c4r;
    int rank = 0;
#pragma unroll
    for (int t2 = 0; t2 < NT; ++t2) {
        int vv = __shfl(my, t2);
        rank += (vv < my) ? 1 : 0;
    }
    if (lane < NT) {
        out[NB * NQ * NT + b * NT + rank] = (float)my;              // pred_idx
        out[NB * NQ * NT + NB * NT + b * NT + rank] = (float)lane;  // tgt_idx
    }
}

// ---------------------------------------------------------------------------
extern "C" void kernel_launch(void* const* d_in, const int* in_sizes, int n_in,
                              void* d_out, int out_size, void* d_ws, size_t ws_size,
                              hipStream_t stream) {
    const float* pred_logits = (const float*)d_in[0];   // [4,100,81]
    const float* pred_masks  = (const float*)d_in[1];   // [4,100,256,256]
    const float* tgt_masks   = (const float*)d_in[2];   // [4,20,512,512]
    const int*   tgt_labels  = (const int*)d_in[3];     // [4,20]
    float* out = (float*)d_out;

    char* ws = (char*)d_ws;
    float* A_part  = (float*)ws;                                      // NB*NQR*SC*TP
    float* D_part  = A_part + (size_t)NB * NQR * SC * TP;
    float* Sp_part = D_part + (size_t)NB * NQR * SC * TP;             // NB*NQ*SC

    k_main<<<NB * SC, 256, 0, stream>>>(pred_masks, tgt_masks, A_part, D_part, Sp_part);
    k_assemble<<<NB * NQ, 256, 0, stream>>>(pred_logits, tgt_labels, A_part, D_part,
                                            Sp_part, out);
    k_lsa<<<NB, 64, 0, stream>>>(out, out);
}